// Round 1
// baseline (555.632 us; speedup 1.0000x reference)
//
#include <hip/hip_runtime.h>
#include <math.h>

#define TPB 256

// 3x3 16ch -> 16ch conv on 15x15 padded channels-last LDS tiles.
// Computes only i,j in [0,12) (the reference's truncated range); writes interior
// [1..12]x[1..12]; surrounding zeros are preserved from buffer init.
__device__ __forceinline__ void conv16x16(const float* __restrict__ src,
                                          float* __restrict__ dst,
                                          const float* __restrict__ Kg,
                                          int tid) {
    if (tid < 192) {
        const int o = tid & 15;
        const int j = tid >> 4;        // 0..11
        float acc[12];
#pragma unroll
        for (int i = 0; i < 12; i++) acc[i] = 0.f;
#pragma unroll
        for (int c4 = 0; c4 < 4; c4++) {
#pragma unroll
            for (int kw = 0; kw < 3; kw++) {
                float4 xr[14];
#pragma unroll
                for (int r = 0; r < 14; r++)
                    xr[r] = *(const float4*)&src[(r * 15 + j + kw) * 16 + c4 * 4];
#pragma unroll
                for (int kh = 0; kh < 3; kh++) {
                    // quirk layout: m = c*9 + kh*3 + kw, w = Kg[m*16+o]
                    const int mb = (c4 * 4) * 9 + kh * 3 + kw;
                    const float w0 = Kg[(mb +  0) * 16 + o];
                    const float w1 = Kg[(mb +  9) * 16 + o];
                    const float w2 = Kg[(mb + 18) * 16 + o];
                    const float w3 = Kg[(mb + 27) * 16 + o];
#pragma unroll
                    for (int i = 0; i < 12; i++) {
                        const float4 xv = xr[i + kh];
                        acc[i] = fmaf(xv.x, w0, acc[i]);
                        acc[i] = fmaf(xv.y, w1, acc[i]);
                        acc[i] = fmaf(xv.z, w2, acc[i]);
                        acc[i] = fmaf(xv.w, w3, acc[i]);
                    }
                }
            }
        }
#pragma unroll
        for (int i = 0; i < 12; i++)
            dst[((i + 1) * 15 + (j + 1)) * 16 + o] = fmaxf(acc[i], 0.f);
    }
}

extern "C" __global__ void __launch_bounds__(TPB)
cnn_fused(const float* __restrict__ xg,
          const float* __restrict__ K1, const float* __restrict__ K2,
          const float* __restrict__ K3, const float* __restrict__ K4,
          const float* __restrict__ K5, const float* __restrict__ K6,
          const float* __restrict__ Wfc, const float* __restrict__ bfc,
          float* __restrict__ out)
{
    // 36 KB LDS, aliased:
    //  sA [0,3600)        : 16ch 15x15 channels-last
    //  sB [3600,7200)     : 16ch 15x15 channels-last; first used as sX (3x30x30 planar, 2700)
    //  sH1[7200,9000)     : 15x15x8 channels-last;    later reused as sF (32x6x6 planar, 1152)
    //  sLog[9000,9016)
    __shared__ float smem[9016];
    float* const sA   = smem;
    float* const sB   = smem + 3600;
    float* const sX   = smem + 3600;
    float* const sH1  = smem + 7200;
    float* const sF   = smem + 7200;
    float* const sLog = smem + 9000;

    const int tid = threadIdx.x;
    const int img = blockIdx.x;

    for (int i = tid; i < 9016; i += TPB) smem[i] = 0.f;
    __syncthreads();

    // load image (B,3,28,28) into padded planar sX[3][30][30]
    const float* xi = xg + (size_t)img * 2352;
    for (int i = tid; i < 2352; i += TPB) {
        const int c = i / 784, rem = i - c * 784;
        const int r = rem / 28, col = rem - r * 28;
        sX[c * 900 + (r + 1) * 30 + (col + 1)] = xi[i];
    }
    __syncthreads();

    // ---- L1: 5x5 s2 p1, 3->8, out 13x13 full, ReLU -> sH1 [15][15][8]
    if (tid < 208) {
        const int o  = tid & 7;
        const int jj = tid >> 3;       // 0..25
        const int j  = jj % 13;
        const int ih = jj / 13;        // 0: i=0..6, 1: i=7..12
        const int i0 = ih * 7;
        float acc[7];
#pragma unroll
        for (int q = 0; q < 7; q++) acc[q] = 0.f;
#pragma unroll
        for (int c = 0; c < 3; c++) {
#pragma unroll
            for (int kw = 0; kw < 5; kw++) {
                float xr[17];
#pragma unroll
                for (int r = 0; r < 17; r++) {
                    int row = 2 * i0 + r;
                    row = row > 29 ? 29 : row;   // clamp into zero pad row
                    xr[r] = sX[c * 900 + row * 30 + 2 * j + kw];
                }
#pragma unroll
                for (int kh = 0; kh < 5; kh++) {
                    const float w = K1[(c * 25 + kh * 5 + kw) * 8 + o];
#pragma unroll
                    for (int q = 0; q < 7; q++)
                        acc[q] = fmaf(xr[2 * q + kh], w, acc[q]);
                }
            }
        }
#pragma unroll
        for (int q = 0; q < 7; q++) {
            const int i = i0 + q;
            if (i < 13)
                sH1[((i + 1) * 15 + (j + 1)) * 8 + o] = fmaxf(acc[q], 0.f);
        }
    }
    __syncthreads();

    // ---- L2: 3x3 s1 p1, 8->16, compute i,j<12, ReLU -> sA.
    // Idle threads re-zero sB (it held the input image) for L3's ping-pong.
    if (tid < 192) {
        const int o = tid & 15;
        const int j = tid >> 4;       // 0..11
        float acc[12];
#pragma unroll
        for (int i = 0; i < 12; i++) acc[i] = 0.f;
#pragma unroll
        for (int c4 = 0; c4 < 2; c4++) {
#pragma unroll
            for (int kw = 0; kw < 3; kw++) {
                float4 xr[14];
#pragma unroll
                for (int r = 0; r < 14; r++)
                    xr[r] = *(const float4*)&sH1[(r * 15 + j + kw) * 8 + c4 * 4];
#pragma unroll
                for (int kh = 0; kh < 3; kh++) {
                    const int mb = (c4 * 4) * 9 + kh * 3 + kw;
                    const float w0 = K2[(mb +  0) * 16 + o];
                    const float w1 = K2[(mb +  9) * 16 + o];
                    const float w2 = K2[(mb + 18) * 16 + o];
                    const float w3 = K2[(mb + 27) * 16 + o];
#pragma unroll
                    for (int i = 0; i < 12; i++) {
                        const float4 xv = xr[i + kh];
                        acc[i] = fmaf(xv.x, w0, acc[i]);
                        acc[i] = fmaf(xv.y, w1, acc[i]);
                        acc[i] = fmaf(xv.z, w2, acc[i]);
                        acc[i] = fmaf(xv.w, w3, acc[i]);
                    }
                }
            }
        }
#pragma unroll
        for (int i = 0; i < 12; i++)
            sA[((i + 1) * 15 + (j + 1)) * 16 + o] = fmaxf(acc[i], 0.f);
    } else {
        for (int i = tid - 192; i < 3600; i += 64) sB[i] = 0.f;
    }
    __syncthreads();

    // ---- L3..L5: ping-pong sA <-> sB
#pragma unroll 1
    for (int L = 0; L < 3; L++) {
        const float* Kg = (L == 0) ? K3 : (L == 1) ? K4 : K5;
        const float* src = (L & 1) ? sB : sA;
        float* dst       = (L & 1) ? sA : sB;
        conv16x16(src, dst, Kg, tid);
        __syncthreads();
    }
    // result of L5 is in sB

    // ---- L6: 5x5 s2 p1, 16->32, compute i,j<5, no ReLU -> sF [32][6][6] planar
    if (tid < 160) {
        const int o = tid & 31;
        const int j = tid >> 5;       // 0..4
        float acc[5];
#pragma unroll
        for (int i = 0; i < 5; i++) acc[i] = 0.f;
#pragma unroll
        for (int c4 = 0; c4 < 4; c4++) {
#pragma unroll
            for (int kw = 0; kw < 5; kw++) {
                float4 xr[13];
#pragma unroll
                for (int r = 0; r < 13; r++)
                    xr[r] = *(const float4*)&sB[(r * 15 + 2 * j + kw) * 16 + c4 * 4];
#pragma unroll
                for (int kh = 0; kh < 5; kh++) {
                    const int mb = (c4 * 4) * 25 + kh * 5 + kw;
                    const float w0 = K6[(mb +  0) * 32 + o];
                    const float w1 = K6[(mb + 25) * 32 + o];
                    const float w2 = K6[(mb + 50) * 32 + o];
                    const float w3 = K6[(mb + 75) * 32 + o];
#pragma unroll
                    for (int i = 0; i < 5; i++) {
                        const float4 xv = xr[2 * i + kh];
                        acc[i] = fmaf(xv.x, w0, acc[i]);
                        acc[i] = fmaf(xv.y, w1, acc[i]);
                        acc[i] = fmaf(xv.z, w2, acc[i]);
                        acc[i] = fmaf(xv.w, w3, acc[i]);
                    }
                }
            }
        }
#pragma unroll
        for (int i = 0; i < 5; i++)
            sF[o * 36 + i * 6 + j] = acc[i];
        // truncated last row/col of the 6x6 map are zero (sF aliases stale sH1)
        sF[o * 36 + 30 + j]    = 0.f;   // (i=5, j)
        sF[o * 36 + j * 6 + 5] = 0.f;   // (i=j, 5)
        if (j == 0) sF[o * 36 + 35] = 0.f; // (5,5)
    }
    __syncthreads();

    // ---- FC: logits[c] = sF . Wfc[c] + bfc[c]; 16 lanes per class
    if (tid < 160) {
        const int c = tid >> 4;       // 0..9
        const int l = tid & 15;
        const float4* fv = (const float4*)(sF + l * 72);
        const float4* wv = (const float4*)(Wfc + c * 1152 + l * 72);
        float p = 0.f;
#pragma unroll
        for (int m = 0; m < 18; m++) {
            const float4 a = fv[m];
            const float4 b = wv[m];
            p = fmaf(a.x, b.x, p);
            p = fmaf(a.y, b.y, p);
            p = fmaf(a.z, b.z, p);
            p = fmaf(a.w, b.w, p);
        }
        p += __shfl_down(p, 8, 16);
        p += __shfl_down(p, 4, 16);
        p += __shfl_down(p, 2, 16);
        p += __shfl_down(p, 1, 16);
        if (l == 0) sLog[c] = p + bfc[c];
    }
    __syncthreads();

    // ---- softmax over 10 logits
    if (tid < 10) {
        float mx = sLog[0];
#pragma unroll
        for (int k = 1; k < 10; k++) mx = fmaxf(mx, sLog[k]);
        float s = 0.f;
#pragma unroll
        for (int k = 0; k < 10; k++) s += expf(sLog[k] - mx);
        out[(size_t)img * 10 + tid] = expf(sLog[tid] - mx) / s;
    }
}

extern "C" void kernel_launch(void* const* d_in, const int* in_sizes, int n_in,
                              void* d_out, int out_size, void* d_ws, size_t ws_size,
                              hipStream_t stream) {
    const float* x   = (const float*)d_in[0];
    const float* K1  = (const float*)d_in[1];
    const float* K2  = (const float*)d_in[2];
    const float* K3  = (const float*)d_in[3];
    const float* K4  = (const float*)d_in[4];
    const float* K5  = (const float*)d_in[5];
    const float* K6  = (const float*)d_in[6];
    const float* Wfc = (const float*)d_in[7];
    const float* bfc = (const float*)d_in[8];
    float* out = (float*)d_out;

    const int B = in_sizes[0] / 2352;   // 8192
    cnn_fused<<<B, TPB, 0, stream>>>(x, K1, K2, K3, K4, K5, K6, Wfc, bfc, out);
}

// Round 2
// 385.269 us; speedup vs baseline: 1.4422x; 1.4422x over previous
//
#include <hip/hip_runtime.h>
#include <math.h>

#define TPB 256

typedef __attribute__((ext_vector_type(8))) short short8;
typedef __attribute__((ext_vector_type(4))) float f32x4;

__device__ __forceinline__ f32x4 MFMA(short8 a, short8 b, f32x4 c) {
    return __builtin_amdgcn_mfma_f32_16x16x32_bf16(a, b, c, 0, 0, 0);
}

__device__ __forceinline__ unsigned short f2bf(float f) {
    unsigned int u = __builtin_bit_cast(unsigned int, f);
    u += 0x7FFFu + ((u >> 16) & 1u);           // round-to-nearest-even
    return (unsigned short)(u >> 16);
}
__device__ __forceinline__ float bf2f(unsigned short h) {
    unsigned int u = ((unsigned int)h) << 16;
    return __builtin_bit_cast(float, u);
}

// ---- 3x3 s1 p1 conv, cin=8 -> cout=16, MFMA 16x16x32, split bf16 (hi/lo).
// K' order: k' = tap*8 + c  (tap = kh*3+kw). Quirk weights: Kg[(c*9+tap)*16+o].
// src: 15x15x8 channels-last hi/lo planes. dst: 15x15x16 hi/lo planes, ReLU.
__device__ __forceinline__ void conv8(const unsigned short* __restrict__ sHi,
                                      const unsigned short* __restrict__ sLo,
                                      unsigned short* __restrict__ dHi,
                                      unsigned short* __restrict__ dLo,
                                      const float* __restrict__ Kg,
                                      int wave, int lane, int rot)
{
    const int o   = lane & 15;
    const int lhi = lane >> 4;                 // k-chunk 0..3
    short8 Bhi[3], Blo[3];
#pragma unroll
    for (int s = 0; s < 3; s++) {
        const int t = s * 4 + lhi;             // tap 0..11 (>8 = zero pad)
        float w[8];
#pragma unroll
        for (int j = 0; j < 8; j++)
            w[j] = (t < 9) ? Kg[(j * 9 + t) * 16 + o] : 0.f;
#pragma unroll
        for (int j = 0; j < 8; j++) {
            const unsigned short h = f2bf(w[j]);
            Bhi[s][j] = (short)h;
            Blo[s][j] = (short)f2bf(w[j] - bf2f(h));
        }
    }
    const int r0 = lane & 15;                  // A row within M-tile
    for (int m = (wave + rot) & 3; m < 9; m += 4) {
        const int p  = m * 16 + r0;            // output position 0..143
        const int ip = (p * 683) >> 13;        // p / 12
        const int jp = p - 12 * ip;
        f32x4 acc = {0.f, 0.f, 0.f, 0.f};
#pragma unroll
        for (int s = 0; s < 3; s++) {
            const int t  = s * 4 + lhi;
            const int tt = t > 8 ? 8 : t;      // clamp addr; B is zero there
            const int kh = (tt * 11) >> 5;     // tt / 3
            const int kw = tt - 3 * kh;
            const int ad = ((ip + kh) * 15 + (jp + kw)) * 8;
            const short8 Ahi = *(const short8*)(sHi + ad);
            const short8 Alo = *(const short8*)(sLo + ad);
            acc = MFMA(Ahi, Bhi[s], acc);
            acc = MFMA(Alo, Bhi[s], acc);
            acc = MFMA(Ahi, Blo[s], acc);
        }
        const int p0 = m * 16 + lhi * 4;       // C rows: (lane>>4)*4 + reg
#pragma unroll
        for (int r = 0; r < 4; r++) {
            const int pp = p0 + r;
            const int ii = (pp * 683) >> 13;
            const int jj = pp - 12 * ii;
            const float v = fmaxf(acc[r], 0.f);
            const unsigned short h = f2bf(v);
            const int da = ((ii + 1) * 15 + (jj + 1)) * 16 + o;
            dHi[da] = h;
            dLo[da] = f2bf(v - bf2f(h));
        }
    }
}

// ---- 3x3 s1 p1 conv, cin=16 -> cout=16. K' = tap*16 + c, 5 K-steps (pad tap 9).
__device__ __forceinline__ void conv16(const unsigned short* __restrict__ sHi,
                                       const unsigned short* __restrict__ sLo,
                                       unsigned short* __restrict__ dHi,
                                       unsigned short* __restrict__ dLo,
                                       const float* __restrict__ Kg,
                                       int wave, int lane, int rot)
{
    const int o     = lane & 15;
    const int lhi   = lane >> 4;
    const int chalf = (lhi & 1) * 8;
    const int tsel  = lhi >> 1;
    short8 Bhi[5], Blo[5];
#pragma unroll
    for (int s = 0; s < 5; s++) {
        const int t = 2 * s + tsel;            // tap 0..9 (9 = zero pad)
        float w[8];
#pragma unroll
        for (int j = 0; j < 8; j++)
            w[j] = (t < 9) ? Kg[((chalf + j) * 9 + t) * 16 + o] : 0.f;
#pragma unroll
        for (int j = 0; j < 8; j++) {
            const unsigned short h = f2bf(w[j]);
            Bhi[s][j] = (short)h;
            Blo[s][j] = (short)f2bf(w[j] - bf2f(h));
        }
    }
    const int r0 = lane & 15;
    for (int m = (wave + rot) & 3; m < 9; m += 4) {
        const int p  = m * 16 + r0;
        const int ip = (p * 683) >> 13;
        const int jp = p - 12 * ip;
        f32x4 acc = {0.f, 0.f, 0.f, 0.f};
#pragma unroll
        for (int s = 0; s < 5; s++) {
            const int t  = 2 * s + tsel;
            const int tt = t > 8 ? 8 : t;
            const int kh = (tt * 11) >> 5;
            const int kw = tt - 3 * kh;
            const int ad = ((ip + kh) * 15 + (jp + kw)) * 16 + chalf;
            const short8 Ahi = *(const short8*)(sHi + ad);
            const short8 Alo = *(const short8*)(sLo + ad);
            acc = MFMA(Ahi, Bhi[s], acc);
            acc = MFMA(Alo, Bhi[s], acc);
            acc = MFMA(Ahi, Blo[s], acc);
        }
        const int p0 = m * 16 + lhi * 4;
#pragma unroll
        for (int r = 0; r < 4; r++) {
            const int pp = p0 + r;
            const int ii = (pp * 683) >> 13;
            const int jj = pp - 12 * ii;
            const float v = fmaxf(acc[r], 0.f);
            const unsigned short h = f2bf(v);
            const int da = ((ii + 1) * 15 + (jj + 1)) * 16 + o;
            dHi[da] = h;
            dLo[da] = f2bf(v - bf2f(h));
        }
    }
}

extern "C" __global__ void __launch_bounds__(TPB)
cnn_fused(const float* __restrict__ xg,
          const float* __restrict__ K1, const float* __restrict__ K2,
          const float* __restrict__ K3, const float* __restrict__ K4,
          const float* __restrict__ K5, const float* __restrict__ K6,
          const float* __restrict__ Wfc, const float* __restrict__ bfc,
          float* __restrict__ out)
{
    // byte map:
    //  A region [0,14400): A16hi [0,7200) A16lo [7200,14400)
    //                      A8hi  [0,3600) A8lo  [7200,10800)
    //  B region [14400,28800): B16hi [14400,21600) B16lo [21600,28800)
    //                      sX f32[2700] @14400 ; sF f32[1152] @14400
    //  sLog f32[10] @28800
    __shared__ __align__(16) unsigned char smem[28864];
    unsigned short* const A16hi = (unsigned short*)(smem);
    unsigned short* const A16lo = (unsigned short*)(smem + 7200);
    unsigned short* const A8hi  = (unsigned short*)(smem);
    unsigned short* const A8lo  = (unsigned short*)(smem + 7200);
    unsigned short* const B16hi = (unsigned short*)(smem + 14400);
    unsigned short* const B16lo = (unsigned short*)(smem + 21600);
    float* const sX   = (float*)(smem + 14400);
    float* const sF   = (float*)(smem + 14400);
    float* const sLog = (float*)(smem + 28800);
    unsigned int* const z = (unsigned int*)smem;

    const int tid  = threadIdx.x;
    const int lane = tid & 63;
    const int wave = tid >> 6;
    const int img  = blockIdx.x;

    for (int i = tid; i < 7216; i += TPB) z[i] = 0u;
    __syncthreads();

    // load image (3,28,28) into padded planar sX[3][30][30]
    const float* xi = xg + (size_t)img * 2352;
    for (int i = tid; i < 2352; i += TPB) {
        const int c = i / 784, rem = i - c * 784;
        const int r = rem / 28, col = rem - r * 28;
        sX[c * 900 + (r + 1) * 30 + (col + 1)] = xi[i];
    }
    __syncthreads();

    // ---- L1: 5x5 s2 p1, 3->8, 13x13 full, ReLU, fp32 VALU -> A8 hi/lo planes
    if (tid < 208) {
        const int o  = tid & 7;
        const int jj = tid >> 3;
        const int j  = jj % 13;
        const int i0 = (jj / 13) * 7;
        float acc[7];
#pragma unroll
        for (int q = 0; q < 7; q++) acc[q] = 0.f;
#pragma unroll
        for (int c = 0; c < 3; c++) {
#pragma unroll
            for (int kw = 0; kw < 5; kw++) {
                float xr[17];
#pragma unroll
                for (int r = 0; r < 17; r++) {
                    int row = 2 * i0 + r;
                    row = row > 29 ? 29 : row;
                    xr[r] = sX[c * 900 + row * 30 + 2 * j + kw];
                }
#pragma unroll
                for (int kh = 0; kh < 5; kh++) {
                    const float w = K1[(c * 25 + kh * 5 + kw) * 8 + o];
#pragma unroll
                    for (int q = 0; q < 7; q++)
                        acc[q] = fmaf(xr[2 * q + kh], w, acc[q]);
                }
            }
        }
#pragma unroll
        for (int q = 0; q < 7; q++) {
            const int i = i0 + q;
            if (i < 13) {
                const float v = fmaxf(acc[q], 0.f);
                const unsigned short h = f2bf(v);
                const int da = ((i + 1) * 15 + (j + 1)) * 8 + o;
                A8hi[da] = h;
                A8lo[da] = f2bf(v - bf2f(h));
            }
        }
    }
    __syncthreads();

    // zero B region (sX dead) for L2's ring
    for (int i = tid; i < 3600; i += TPB) z[3600 + i] = 0u;
    __syncthreads();

    conv8(A8hi, A8lo, B16hi, B16lo, K2, wave, lane, 0);   // L2
    __syncthreads();

    // zero A region (A8 consumed) for L3's ring
    for (int i = tid; i < 3600; i += TPB) z[i] = 0u;
    __syncthreads();

    conv16(B16hi, B16lo, A16hi, A16lo, K3, wave, lane, 1); // L3
    __syncthreads();
    conv16(A16hi, A16lo, B16hi, B16lo, K4, wave, lane, 2); // L4 (B ring still zero)
    __syncthreads();
    conv16(B16hi, B16lo, A16hi, A16lo, K5, wave, lane, 3); // L5 (A ring still zero)
    __syncthreads();

    // zero sF (B region free after L5 read)
    for (int i = tid; i < 1152; i += TPB) z[3600 + i] = 0u;
    __syncthreads();

    // ---- L6: 5x5 s2 p1, 16->32, i,j<5, no ReLU. MFMA split. K'=tap*16+c, 13 steps.
    {
        const int mt  = wave >> 1;
        const int n0  = (wave & 1) * 16;
        const int o   = n0 + (lane & 15);
        const int lhi = lane >> 4;
        const int chalf = (lhi & 1) * 8;
        const int tsel  = lhi >> 1;
        const int pr = mt * 16 + (lane & 15);
        const int pe = pr < 25 ? pr : 0;
        const int ia = (pe * 52) >> 8;          // pe / 5
        const int ja = pe - 5 * ia;
        f32x4 acc = {0.f, 0.f, 0.f, 0.f};
        for (int s = 0; s < 13; s++) {
            const int t  = 2 * s + tsel;        // tap 0..25 (25 = pad)
            const int tt = t > 24 ? 24 : t;
            const int kh = (tt * 52) >> 8;      // tt / 5
            const int kw = tt - 5 * kh;
            const int ad = ((2 * ia + kh) * 15 + (2 * ja + kw)) * 16 + chalf;
            const short8 Ahi = *(const short8*)(A16hi + ad);
            const short8 Alo = *(const short8*)(A16lo + ad);
            float w[8];
#pragma unroll
            for (int j = 0; j < 8; j++)
                w[j] = (t < 25) ? K6[((chalf + j) * 25 + t) * 32 + o] : 0.f;
            short8 Bh, Bl;
#pragma unroll
            for (int j = 0; j < 8; j++) {
                const unsigned short h = f2bf(w[j]);
                Bh[j] = (short)h;
                Bl[j] = (short)f2bf(w[j] - bf2f(h));
            }
            acc = MFMA(Ahi, Bh, acc);
            acc = MFMA(Alo, Bh, acc);
            acc = MFMA(Ahi, Bl, acc);
        }
        const int p0 = mt * 16 + lhi * 4;
#pragma unroll
        for (int r = 0; r < 4; r++) {
            const int pp = p0 + r;
            if (pp < 25) {
                const int ii = (pp * 52) >> 8;
                const int jj = pp - 5 * ii;
                sF[o * 36 + ii * 6 + jj] = acc[r];
            }
        }
    }
    __syncthreads();

    // ---- FC: logits[c] = sF . Wfc[c] + bfc[c]; 16 lanes per class (fp32)
    if (tid < 160) {
        const int c = tid >> 4;
        const int l = tid & 15;
        const float4* fv = (const float4*)(sF + l * 72);
        const float4* wv = (const float4*)(Wfc + c * 1152 + l * 72);
        float p = 0.f;
#pragma unroll
        for (int m = 0; m < 18; m++) {
            const float4 a = fv[m];
            const float4 b = wv[m];
            p = fmaf(a.x, b.x, p);
            p = fmaf(a.y, b.y, p);
            p = fmaf(a.z, b.z, p);
            p = fmaf(a.w, b.w, p);
        }
        p += __shfl_down(p, 8, 16);
        p += __shfl_down(p, 4, 16);
        p += __shfl_down(p, 2, 16);
        p += __shfl_down(p, 1, 16);
        if (l == 0) sLog[c] = p + bfc[c];
    }
    __syncthreads();

    // ---- softmax over 10 logits
    if (tid < 10) {
        float mx = sLog[0];
#pragma unroll
        for (int k = 1; k < 10; k++) mx = fmaxf(mx, sLog[k]);
        float s = 0.f;
#pragma unroll
        for (int k = 0; k < 10; k++) s += expf(sLog[k] - mx);
        out[(size_t)img * 10 + tid] = expf(sLog[tid] - mx) / s;
    }
}

extern "C" void kernel_launch(void* const* d_in, const int* in_sizes, int n_in,
                              void* d_out, int out_size, void* d_ws, size_t ws_size,
                              hipStream_t stream) {
    const float* x   = (const float*)d_in[0];
    const float* K1  = (const float*)d_in[1];
    const float* K2  = (const float*)d_in[2];
    const float* K3  = (const float*)d_in[3];
    const float* K4  = (const float*)d_in[4];
    const float* K5  = (const float*)d_in[5];
    const float* K6  = (const float*)d_in[6];
    const float* Wfc = (const float*)d_in[7];
    const float* bfc = (const float*)d_in[8];
    float* out = (float*)d_out;

    const int B = in_sizes[0] / 2352;   // 8192
    cnn_fused<<<B, TPB, 0, stream>>>(x, K1, K2, K3, K4, K5, K6, Wfc, bfc, out);
}

// Round 3
// 296.958 us; speedup vs baseline: 1.8711x; 1.2974x over previous
//
#include <hip/hip_runtime.h>
#include <math.h>

#define TPB 256

typedef __attribute__((ext_vector_type(8))) short short8;
typedef __attribute__((ext_vector_type(4))) float f32x4;
typedef unsigned short u16;

__device__ __forceinline__ f32x4 MFMA(short8 a, short8 b, f32x4 c) {
    return __builtin_amdgcn_mfma_f32_16x16x32_bf16(a, b, c, 0, 0, 0);
}
__device__ __forceinline__ u16 f2bf(float f) {
    unsigned int u = __builtin_bit_cast(unsigned int, f);
    u += 0x7FFFu + ((u >> 16) & 1u);            // RNE
    return (u16)(u >> 16);
}
__device__ __forceinline__ float bf2f(u16 h) {
    unsigned int u = ((unsigned int)h) << 16;
    return __builtin_bit_cast(float, u);
}

// ============ weight-fragment pre-kernel ============
// ws layout (short8 slots): entry = slot>>6, lane = slot&63.
//  K2:  ent [0,6)    = s*2+hl                 (s<3)
//  K3:  ent [6,16)   = 6  + s*2+hl            (s<5)
//  K4:  ent [16,26)  = 16 + s*2+hl
//  K5:  ent [26,36)  = 26 + s*2+hl
//  K6:  ent [36,88)  = 36 + s*4+hl*2+nh       (s<13, nh = cout half)
extern "C" __global__ void prep_w(const float* __restrict__ K2, const float* __restrict__ K3,
                                  const float* __restrict__ K4, const float* __restrict__ K5,
                                  const float* __restrict__ K6, short8* __restrict__ W)
{
    const int slot = blockIdx.x * blockDim.x + threadIdx.x;
    if (slot >= 5632) return;
    const int lane = slot & 63;
    const int ent  = slot >> 6;
    const int o    = lane & 15;
    const int lhi  = lane >> 4;
    float w[8];
    int hl;
    if (ent < 6) {                       // K2: k' = tap*8 + c, tap = s*4+lhi
        const int s = ent >> 1; hl = ent & 1;
        const int t = s * 4 + lhi;
#pragma unroll
        for (int j = 0; j < 8; j++)
            w[j] = (t < 9) ? K2[(j * 9 + t) * 16 + o] : 0.f;
    } else if (ent < 36) {               // K3/4/5: k' = tap*16 + c
        const int e  = ent - 6;
        const float* Kg = (e < 10) ? K3 : (e < 20) ? K4 : K5;
        const int el = e % 10;
        const int s  = el >> 1; hl = el & 1;
        const int chalf = (lhi & 1) * 8;
        const int t = 2 * s + (lhi >> 1);
#pragma unroll
        for (int j = 0; j < 8; j++)
            w[j] = (t < 9) ? Kg[((chalf + j) * 9 + t) * 16 + o] : 0.f;
    } else {                             // K6: k' = tap*16 + c, tap<25
        const int e = ent - 36;
        const int s = e >> 2; hl = (e >> 1) & 1;
        const int nh = e & 1;
        const int chalf = (lhi & 1) * 8;
        const int t  = 2 * s + (lhi >> 1);
        const int oo = nh * 16 + o;
#pragma unroll
        for (int j = 0; j < 8; j++)
            w[j] = (t < 25) ? K6[((chalf + j) * 25 + t) * 32 + oo] : 0.f;
    }
    short8 v;
#pragma unroll
    for (int j = 0; j < 8; j++) {
        const u16 h = f2bf(w[j]);
        v[j] = hl ? (short)f2bf(w[j] - bf2f(h)) : (short)h;
    }
    W[slot] = v;
}

// ============ conv helpers (half-channel-plane LDS layout) ============
// 16-ch tensor @ base (shorts): hi half0 [0,1800), hi half1 [1800,3600),
//                               lo half0 [3600,5400), lo half1 [5400,7200)
// pixel stride = 8 shorts = 16 B -> consecutive pixels walk all 8 LDS granules.

__device__ __forceinline__ void conv8(const u16* __restrict__ s0,   // 8-ch src: hi [0,1800), lo +3600
                                      u16* __restrict__ d0,
                                      const short8* __restrict__ Wt,
                                      int wave, int lane, int rot)
{
    const int o   = lane & 15;
    const int lhi = lane >> 4;
    short8 Bhi[3], Blo[3];
#pragma unroll
    for (int s = 0; s < 3; s++) {
        Bhi[s] = Wt[(s * 2 + 0) * 64 + lane];
        Blo[s] = Wt[(s * 2 + 1) * 64 + lane];
    }
    const u16* sl = s0 + 3600;
    const int r0 = lane & 15;

    auto tile = [&](int m) {
        const int p  = m * 16 + r0;
        const int ip = (p * 683) >> 13;          // p/12
        const int jp = p - 12 * ip;
        f32x4 acc = {0.f, 0.f, 0.f, 0.f};
#pragma unroll
        for (int s = 0; s < 3; s++) {
            const int t  = s * 4 + lhi;
            const int tt = t > 8 ? 8 : t;
            const int kh = (tt * 11) >> 5;       // tt/3
            const int kw = tt - 3 * kh;
            const int px = (ip + kh) * 15 + (jp + kw);
            const short8 Ahi = *(const short8*)(s0 + px * 8);
            const short8 Alo = *(const short8*)(sl + px * 8);
            acc = MFMA(Ahi, Bhi[s], acc);
            acc = MFMA(Alo, Bhi[s], acc);
            acc = MFMA(Ahi, Blo[s], acc);
        }
        const int p0 = m * 16 + lhi * 4;
#pragma unroll
        for (int r = 0; r < 4; r++) {
            const int pp = p0 + r;
            const int ii = (pp * 683) >> 13;
            const int jj = pp - 12 * ii;
            const float v = fmaxf(acc[r], 0.f);
            const u16 h = f2bf(v);
            const int px2 = (ii + 1) * 15 + (jj + 1);
            const int da  = (o >> 3) * 1800 + px2 * 8 + (o & 7);
            d0[da]        = h;
            d0[da + 3600] = f2bf(v - bf2f(h));
        }
    };
    const int m0 = (wave + rot) & 3;
    tile(m0);
    tile(m0 + 4);
    if (m0 == 0) tile(8);
}

__device__ __forceinline__ void conv16(const u16* __restrict__ s0,
                                       u16* __restrict__ d0,
                                       const short8* __restrict__ Wt,
                                       int wave, int lane, int rot)
{
    const int o    = lane & 15;
    const int lhi  = lane >> 4;
    const int hsel = lhi & 1;
    const int tsel = lhi >> 1;
    short8 Bhi[5], Blo[5];
#pragma unroll
    for (int s = 0; s < 5; s++) {
        Bhi[s] = Wt[(s * 2 + 0) * 64 + lane];
        Blo[s] = Wt[(s * 2 + 1) * 64 + lane];
    }
    const u16* sh = s0 + hsel * 1800;
    const u16* sl = sh + 3600;
    const int r0 = lane & 15;

    auto tile = [&](int m) {
        const int p  = m * 16 + r0;
        const int ip = (p * 683) >> 13;
        const int jp = p - 12 * ip;
        f32x4 acc = {0.f, 0.f, 0.f, 0.f};
#pragma unroll
        for (int s = 0; s < 5; s++) {
            const int t  = 2 * s + tsel;
            const int tt = t > 8 ? 8 : t;
            const int kh = (tt * 11) >> 5;
            const int kw = tt - 3 * kh;
            const int px = (ip + kh) * 15 + (jp + kw);
            const short8 Ahi = *(const short8*)(sh + px * 8);
            const short8 Alo = *(const short8*)(sl + px * 8);
            acc = MFMA(Ahi, Bhi[s], acc);
            acc = MFMA(Alo, Bhi[s], acc);
            acc = MFMA(Ahi, Blo[s], acc);
        }
        const int p0 = m * 16 + lhi * 4;
#pragma unroll
        for (int r = 0; r < 4; r++) {
            const int pp = p0 + r;
            const int ii = (pp * 683) >> 13;
            const int jj = pp - 12 * ii;
            const float v = fmaxf(acc[r], 0.f);
            const u16 h = f2bf(v);
            const int px2 = (ii + 1) * 15 + (jj + 1);
            const int da  = (o >> 3) * 1800 + px2 * 8 + (o & 7);
            d0[da]        = h;
            d0[da + 3600] = f2bf(v - bf2f(h));
        }
    };
    const int m0 = (wave + rot) & 3;
    tile(m0);
    tile(m0 + 4);
    if (m0 == 0) tile(8);
}

// ============ main fused kernel ============
extern "C" __global__ void __launch_bounds__(TPB, 4)
cnn_fused(const float* __restrict__ xg, const float* __restrict__ K1,
          const float* __restrict__ Wfc, const float* __restrict__ bfc,
          const short8* __restrict__ W, float* __restrict__ out)
{
    // byte map:
    //  A region [0,14400)     : 16-ch tensor (or 8-ch: hi [0,3600), lo [7200,10800))
    //  B region [14400,28800) : 16-ch tensor; also sX f32[2700] / sF f32[1152]
    //  sLog [28800,28840)
    __shared__ __align__(16) unsigned char smem[28864];
    u16*   const Ah   = (u16*)smem;
    u16*   const Bh   = (u16*)(smem + 14400);
    float* const sX   = (float*)(smem + 14400);
    float* const sF   = (float*)(smem + 14400);
    float* const sLog = (float*)(smem + 28800);
    uint4* const z4   = (uint4*)smem;
    const uint4 Z = {0u, 0u, 0u, 0u};

    const int tid  = threadIdx.x;
    const int lane = tid & 63;
    const int wave = tid >> 6;
    const int img  = blockIdx.x;

    // zero A region; stage image into sX [3][30][30] (padded planar)
    for (int i = tid; i < 900; i += TPB) z4[i] = Z;
    const float4* xi4 = (const float4*)(xg + (size_t)img * 2352);
    for (int i4 = tid; i4 < 588; i4 += TPB) {
        const float4 v = xi4[i4];
        const int c = i4 / 196;
        const int rem = i4 - c * 196;
        const int r = rem / 7;
        const int q = rem - r * 7;
        float* dp = sX + c * 900 + (r + 1) * 30 + q * 4 + 1;
        dp[0] = v.x; dp[1] = v.y; dp[2] = v.z; dp[3] = v.w;
    }
    __syncthreads();

    // ---- L1: 5x5 s2 p1, 3->8, 13x13 full, ReLU, fp32 VALU -> A8 hi/lo
    if (tid < 208) {
        const int o  = tid & 7;
        const int jj = tid >> 3;
        const int j  = jj % 13;
        const int i0 = (jj / 13) * 7;
        float acc[7];
#pragma unroll
        for (int q = 0; q < 7; q++) acc[q] = 0.f;
#pragma unroll
        for (int c = 0; c < 3; c++) {
            const float* bp = sX + c * 900 + 2 * j;
#pragma unroll
            for (int kwp = 0; kwp < 2; kwp++) {  // kw pairs (0,1),(2,3)
                float2 xr[17];
#pragma unroll
                for (int r = 0; r < 17; r++) {
                    int row = 2 * i0 + r;
                    row = row > 29 ? 29 : row;
                    xr[r] = *(const float2*)(bp + row * 30 + 2 * kwp);
                }
#pragma unroll
                for (int kh = 0; kh < 5; kh++) {
                    const float w0 = K1[(c * 25 + kh * 5 + 2 * kwp) * 8 + o];
                    const float w1 = K1[(c * 25 + kh * 5 + 2 * kwp + 1) * 8 + o];
#pragma unroll
                    for (int q = 0; q < 7; q++) {
                        acc[q] = fmaf(xr[2 * q + kh].x, w0, acc[q]);
                        acc[q] = fmaf(xr[2 * q + kh].y, w1, acc[q]);
                    }
                }
            }
            {   // kw = 4
                float xs[17];
#pragma unroll
                for (int r = 0; r < 17; r++) {
                    int row = 2 * i0 + r;
                    row = row > 29 ? 29 : row;
                    xs[r] = bp[row * 30 + 4];
                }
#pragma unroll
                for (int kh = 0; kh < 5; kh++) {
                    const float w4 = K1[(c * 25 + kh * 5 + 4) * 8 + o];
#pragma unroll
                    for (int q = 0; q < 7; q++)
                        acc[q] = fmaf(xs[2 * q + kh], w4, acc[q]);
                }
            }
        }
#pragma unroll
        for (int q = 0; q < 7; q++) {
            const int i = i0 + q;
            if (i < 13) {
                const float v = fmaxf(acc[q], 0.f);
                const u16 h = f2bf(v);
                const int da = ((i + 1) * 15 + (j + 1)) * 8 + o;
                Ah[da]        = h;
                Ah[da + 3600] = f2bf(v - bf2f(h));
            }
        }
    }
    __syncthreads();

    // zero B region (sX dead)
    for (int i = tid + 900; i < 1800; i += TPB) z4[i] = Z;
    __syncthreads();

    conv8(Ah, Bh, W, wave, lane, 0);               // L2: A8 -> B16
    __syncthreads();

    for (int i = tid; i < 900; i += TPB) z4[i] = Z; // zero A region
    __syncthreads();

    conv16(Bh, Ah, W + 384, wave, lane, 1);        // L3
    __syncthreads();
    conv16(Ah, Bh, W + 1024, wave, lane, 2);       // L4
    __syncthreads();
    conv16(Bh, Ah, W + 1664, wave, lane, 3);       // L5
    __syncthreads();

    // zero sF region [14400,19008) = z4[900,1188)
    for (int i = tid + 900; i < 1188; i += TPB) z4[i] = Z;
    __syncthreads();

    // ---- L6: 5x5 s2 p1, 16->32, i,j<5, no ReLU -> sF [32][6][6] planar
    {
        const short8* Wt6 = W + 2304;
        const int mt   = wave >> 1;
        const int nh   = wave & 1;
        const int lhi  = lane >> 4;
        const int hsel = lhi & 1;
        const int tsel = lhi >> 1;
        const int o    = nh * 16 + (lane & 15);
        const int pr = mt * 16 + (lane & 15);
        const int pe = pr < 25 ? pr : 0;
        const int ia = (pe * 52) >> 8;            // pe/5
        const int ja = pe - 5 * ia;
        const u16* sh = Ah + hsel * 1800;
        const u16* sl = sh + 3600;
        f32x4 acc = {0.f, 0.f, 0.f, 0.f};
#pragma unroll 4
        for (int s = 0; s < 13; s++) {
            const int t  = 2 * s + tsel;
            const int tt = t > 24 ? 24 : t;
            const int kh = (tt * 52) >> 8;        // tt/5
            const int kw = tt - 5 * kh;
            const int px = (2 * ia + kh) * 15 + (2 * ja + kw);
            const short8 Ahi = *(const short8*)(sh + px * 8);
            const short8 Alo = *(const short8*)(sl + px * 8);
            const short8 Bh2 = Wt6[((s * 2 + 0) * 2 + nh) * 64 + lane];
            const short8 Bl2 = Wt6[((s * 2 + 1) * 2 + nh) * 64 + lane];
            acc = MFMA(Ahi, Bh2, acc);
            acc = MFMA(Alo, Bh2, acc);
            acc = MFMA(Ahi, Bl2, acc);
        }
        const int p0 = mt * 16 + lhi * 4;
#pragma unroll
        for (int r = 0; r < 4; r++) {
            const int pp = p0 + r;
            if (pp < 25) {
                const int ii = (pp * 52) >> 8;
                const int jj = pp - 5 * ii;
                sF[o * 36 + ii * 6 + jj] = acc[r];
            }
        }
    }
    __syncthreads();

    // ---- FC: logits[c] = sF . Wfc[c] + bfc[c]
    if (tid < 160) {
        const int c = tid >> 4;
        const int l = tid & 15;
        const float4* fv = (const float4*)(sF + l * 72);
        const float4* wv = (const float4*)(Wfc + c * 1152 + l * 72);
        float p = 0.f;
#pragma unroll
        for (int m = 0; m < 18; m++) {
            const float4 a = fv[m];
            const float4 b = wv[m];
            p = fmaf(a.x, b.x, p);
            p = fmaf(a.y, b.y, p);
            p = fmaf(a.z, b.z, p);
            p = fmaf(a.w, b.w, p);
        }
        p += __shfl_down(p, 8, 16);
        p += __shfl_down(p, 4, 16);
        p += __shfl_down(p, 2, 16);
        p += __shfl_down(p, 1, 16);
        if (l == 0) sLog[c] = p + bfc[c];
    }
    __syncthreads();

    // ---- softmax
    if (tid < 10) {
        float mx = sLog[0];
#pragma unroll
        for (int k = 1; k < 10; k++) mx = fmaxf(mx, sLog[k]);
        float s = 0.f;
#pragma unroll
        for (int k = 0; k < 10; k++) s += expf(sLog[k] - mx);
        out[(size_t)img * 10 + tid] = expf(sLog[tid] - mx) / s;
    }
}

extern "C" void kernel_launch(void* const* d_in, const int* in_sizes, int n_in,
                              void* d_out, int out_size, void* d_ws, size_t ws_size,
                              hipStream_t stream) {
    const float* x   = (const float*)d_in[0];
    const float* K1  = (const float*)d_in[1];
    const float* K2  = (const float*)d_in[2];
    const float* K3  = (const float*)d_in[3];
    const float* K4  = (const float*)d_in[4];
    const float* K5  = (const float*)d_in[5];
    const float* K6  = (const float*)d_in[6];
    const float* Wfc = (const float*)d_in[7];
    const float* bfc = (const float*)d_in[8];
    float* out = (float*)d_out;
    short8* W = (short8*)d_ws;

    prep_w<<<22, TPB, 0, stream>>>(K2, K3, K4, K5, K6, W);

    const int B = in_sizes[0] / 2352;   // 8192
    cnn_fused<<<B, TPB, 0, stream>>>(x, K1, Wfc, bfc, W, out);
}

// Round 5
// 220.137 us; speedup vs baseline: 2.5240x; 1.3490x over previous
//
#include <hip/hip_runtime.h>
#include <math.h>

#define TPB 256

typedef __attribute__((ext_vector_type(8))) short short8;
typedef __attribute__((ext_vector_type(4))) float f32x4;
typedef unsigned short u16;

__device__ __forceinline__ f32x4 MFMA(short8 a, short8 b, f32x4 c) {
    return __builtin_amdgcn_mfma_f32_16x16x32_bf16(a, b, c, 0, 0, 0);
}
__device__ __forceinline__ u16 f2bf(float f) {
    unsigned int u = __builtin_bit_cast(unsigned int, f);
    u += 0x7FFFu + ((u >> 16) & 1u);            // RNE
    return (u16)(u >> 16);
}
__device__ __forceinline__ float bf2f(u16 h) {
    unsigned int u = ((unsigned int)h) << 16;
    return __builtin_bit_cast(float, u);
}

// ============ weight-fragment pre-kernel ============
// ws layout (short8 slots): entry = slot>>6, lane = slot&63.
//  K2:  ent [0,6)    = s*2+hl                 (s<3)
//  K3:  ent [6,16)   = 6  + s*2+hl            (s<5)
//  K4:  ent [16,26)  = 16 + s*2+hl
//  K5:  ent [26,36)  = 26 + s*2+hl
//  K6:  ent [36,88)  = 36 + s*4+hl*2+nh       (s<13, nh = cout half)
extern "C" __global__ void prep_w(const float* __restrict__ K2, const float* __restrict__ K3,
                                  const float* __restrict__ K4, const float* __restrict__ K5,
                                  const float* __restrict__ K6, short8* __restrict__ W)
{
    const int slot = blockIdx.x * blockDim.x + threadIdx.x;
    if (slot >= 5632) return;
    const int lane = slot & 63;
    const int ent  = slot >> 6;
    const int o    = lane & 15;
    const int lhi  = lane >> 4;
    float w[8];
    int hl;
    if (ent < 6) {                       // K2: k' = tap*8 + c, tap = s*4+lhi
        const int s = ent >> 1; hl = ent & 1;
        const int t = s * 4 + lhi;
#pragma unroll
        for (int j = 0; j < 8; j++)
            w[j] = (t < 9) ? K2[(j * 9 + t) * 16 + o] : 0.f;
    } else if (ent < 36) {               // K3/4/5: k' = tap*16 + c
        const int e  = ent - 6;
        const float* Kg = (e < 10) ? K3 : (e < 20) ? K4 : K5;
        const int el = e % 10;
        const int s  = el >> 1; hl = el & 1;
        const int chalf = (lhi & 1) * 8;
        const int t = 2 * s + (lhi >> 1);
#pragma unroll
        for (int j = 0; j < 8; j++)
            w[j] = (t < 9) ? Kg[((chalf + j) * 9 + t) * 16 + o] : 0.f;
    } else {                             // K6: k' = tap*16 + c, tap<25
        const int e = ent - 36;
        const int s = e >> 2; hl = (e >> 1) & 1;
        const int nh = e & 1;
        const int chalf = (lhi & 1) * 8;
        const int t  = 2 * s + (lhi >> 1);
        const int oo = nh * 16 + o;
#pragma unroll
        for (int j = 0; j < 8; j++)
            w[j] = (t < 25) ? K6[((chalf + j) * 25 + t) * 32 + oo] : 0.f;
    }
    short8 v;
#pragma unroll
    for (int j = 0; j < 8; j++) {
        const u16 h = f2bf(w[j]);
        v[j] = hl ? (short)f2bf(w[j] - bf2f(h)) : (short)h;
    }
    W[slot] = v;
}

// ============ conv helpers (half-channel-plane LDS layout) ============
// 16-ch tensor @ base (shorts): hi half0 [0,1800), hi half1 [1800,3600),
//                               lo half0 [3600,5400), lo half1 [5400,7200)
// pixel stride = 8 shorts = 16 B -> consecutive pixels walk all 8 LDS granules.

__device__ __forceinline__ void conv8(const u16* __restrict__ s0,   // 8-ch src: hi [0,1800), lo +3600
                                      u16* __restrict__ d0,
                                      const short8* __restrict__ Wt,
                                      int wave, int lane, int rot)
{
    const int o   = lane & 15;
    const int lhi = lane >> 4;
    short8 Bhi[3], Blo[3];
#pragma unroll
    for (int s = 0; s < 3; s++) {
        Bhi[s] = Wt[(s * 2 + 0) * 64 + lane];
        Blo[s] = Wt[(s * 2 + 1) * 64 + lane];
    }
    const u16* sl = s0 + 3600;
    const int r0 = lane & 15;

    auto tile = [&](int m) {
        const int p  = m * 16 + r0;
        const int ip = (p * 683) >> 13;          // p/12
        const int jp = p - 12 * ip;
        f32x4 acc = {0.f, 0.f, 0.f, 0.f};
#pragma unroll
        for (int s = 0; s < 3; s++) {
            const int t  = s * 4 + lhi;
            const int tt = t > 8 ? 8 : t;
            const int kh = (tt * 11) >> 5;       // tt/3
            const int kw = tt - 3 * kh;
            const int px = (ip + kh) * 15 + (jp + kw);
            const short8 Ahi = *(const short8*)(s0 + px * 8);
            const short8 Alo = *(const short8*)(sl + px * 8);
            acc = MFMA(Ahi, Bhi[s], acc);
            acc = MFMA(Alo, Bhi[s], acc);
            acc = MFMA(Ahi, Blo[s], acc);
        }
        const int p0 = m * 16 + lhi * 4;
#pragma unroll
        for (int r = 0; r < 4; r++) {
            const int pp = p0 + r;
            const int ii = (pp * 683) >> 13;
            const int jj = pp - 12 * ii;
            const float v = fmaxf(acc[r], 0.f);
            const u16 h = f2bf(v);
            const int px2 = (ii + 1) * 15 + (jj + 1);
            const int da  = (o >> 3) * 1800 + px2 * 8 + (o & 7);
            d0[da]        = h;
            d0[da + 3600] = f2bf(v - bf2f(h));
        }
    };
    const int m0 = (wave + rot) & 3;
    tile(m0);
    tile(m0 + 4);
    if (m0 == 0) tile(8);
}

__device__ __forceinline__ void conv16(const u16* __restrict__ s0,
                                       u16* __restrict__ d0,
                                       const short8* __restrict__ Wt,
                                       int wave, int lane, int rot)
{
    const int o    = lane & 15;
    const int lhi  = lane >> 4;
    const int hsel = lhi & 1;
    const int tsel = lhi >> 1;
    short8 Bhi[5], Blo[5];
#pragma unroll
    for (int s = 0; s < 5; s++) {
        Bhi[s] = Wt[(s * 2 + 0) * 64 + lane];
        Blo[s] = Wt[(s * 2 + 1) * 64 + lane];
    }
    const u16* sh = s0 + hsel * 1800;
    const u16* sl = sh + 3600;
    const int r0 = lane & 15;

    auto tile = [&](int m) {
        const int p  = m * 16 + r0;
        const int ip = (p * 683) >> 13;
        const int jp = p - 12 * ip;
        f32x4 acc = {0.f, 0.f, 0.f, 0.f};
#pragma unroll
        for (int s = 0; s < 5; s++) {
            const int t  = 2 * s + tsel;
            const int tt = t > 8 ? 8 : t;
            const int kh = (tt * 11) >> 5;
            const int kw = tt - 3 * kh;
            const int px = (ip + kh) * 15 + (jp + kw);
            const short8 Ahi = *(const short8*)(sh + px * 8);
            const short8 Alo = *(const short8*)(sl + px * 8);
            acc = MFMA(Ahi, Bhi[s], acc);
            acc = MFMA(Alo, Bhi[s], acc);
            acc = MFMA(Ahi, Blo[s], acc);
        }
        const int p0 = m * 16 + lhi * 4;
#pragma unroll
        for (int r = 0; r < 4; r++) {
            const int pp = p0 + r;
            const int ii = (pp * 683) >> 13;
            const int jj = pp - 12 * ii;
            const float v = fmaxf(acc[r], 0.f);
            const u16 h = f2bf(v);
            const int px2 = (ii + 1) * 15 + (jj + 1);
            const int da  = (o >> 3) * 1800 + px2 * 8 + (o & 7);
            d0[da]        = h;
            d0[da + 3600] = f2bf(v - bf2f(h));
        }
    };
    const int m0 = (wave + rot) & 3;
    tile(m0);
    tile(m0 + 4);
    if (m0 == 0) tile(8);
}

// ============ main fused kernel ============
extern "C" __global__ void __launch_bounds__(TPB)
cnn_fused(const float* __restrict__ xg, const float* __restrict__ K1,
          const float* __restrict__ Wfc, const float* __restrict__ bfc,
          const short8* __restrict__ W, float* __restrict__ out)
{
    // byte map:
    //  A region [0,14400)     : 16-ch tensor (or 8-ch: hi [0,3600), lo [7200,10800))
    //  B region [14400,28800) : 16-ch tensor; also sX f32[2700] / sF f32[1152]
    //  sLog [28800,28840)
    __shared__ __align__(16) unsigned char smem[28864];
    u16*   const Ah   = (u16*)smem;
    u16*   const Bh   = (u16*)(smem + 14400);
    float* const sX   = (float*)(smem + 14400);
    float* const sF   = (float*)(smem + 14400);
    float* const sLog = (float*)(smem + 28800);
    uint4* const z4   = (uint4*)smem;
    const uint4 Z = {0u, 0u, 0u, 0u};

    const int tid  = threadIdx.x;
    const int lane = tid & 63;
    const int wave = tid >> 6;
    const int img  = blockIdx.x;

    // zero ALL of LDS (28864 B = 1804 uint4). LDS content is inherited from
    // whatever block ran here before -- sX's padding ring MUST be zero.
    for (int i = tid; i < 1804; i += TPB) z4[i] = Z;
    __syncthreads();

    // stage image into sX [3][30][30] (padded planar)
    const float4* xi4 = (const float4*)(xg + (size_t)img * 2352);
    for (int i4 = tid; i4 < 588; i4 += TPB) {
        const float4 v = xi4[i4];
        const int c = i4 / 196;
        const int rem = i4 - c * 196;
        const int r = rem / 7;
        const int q = rem - r * 7;
        float* dp = sX + c * 900 + (r + 1) * 30 + q * 4 + 1;
        dp[0] = v.x; dp[1] = v.y; dp[2] = v.z; dp[3] = v.w;
    }
    __syncthreads();

    // ---- L1: 5x5 s2 p1, 3->8, 13x13 full, ReLU, fp32 VALU -> A8 hi/lo
    if (tid < 208) {
        const int o  = tid & 7;
        const int jj = tid >> 3;
        const int j  = jj % 13;
        const int i0 = (jj / 13) * 7;
        float acc[7];
#pragma unroll
        for (int q = 0; q < 7; q++) acc[q] = 0.f;
#pragma unroll
        for (int c = 0; c < 3; c++) {
            const float* bp = sX + c * 900 + 2 * j;
#pragma unroll
            for (int kwp = 0; kwp < 2; kwp++) {  // kw pairs (0,1),(2,3)
                float2 xr[17];
#pragma unroll
                for (int r = 0; r < 17; r++) {
                    int row = 2 * i0 + r;
                    row = row > 29 ? 29 : row;
                    xr[r] = *(const float2*)(bp + row * 30 + 2 * kwp);
                }
#pragma unroll
                for (int kh = 0; kh < 5; kh++) {
                    const float w0 = K1[(c * 25 + kh * 5 + 2 * kwp) * 8 + o];
                    const float w1 = K1[(c * 25 + kh * 5 + 2 * kwp + 1) * 8 + o];
#pragma unroll
                    for (int q = 0; q < 7; q++) {
                        acc[q] = fmaf(xr[2 * q + kh].x, w0, acc[q]);
                        acc[q] = fmaf(xr[2 * q + kh].y, w1, acc[q]);
                    }
                }
            }
            {   // kw = 4
                float xs[17];
#pragma unroll
                for (int r = 0; r < 17; r++) {
                    int row = 2 * i0 + r;
                    row = row > 29 ? 29 : row;
                    xs[r] = bp[row * 30 + 4];
                }
#pragma unroll
                for (int kh = 0; kh < 5; kh++) {
                    const float w4 = K1[(c * 25 + kh * 5 + 4) * 8 + o];
#pragma unroll
                    for (int q = 0; q < 7; q++)
                        acc[q] = fmaf(xs[2 * q + kh], w4, acc[q]);
                }
            }
        }
#pragma unroll
        for (int q = 0; q < 7; q++) {
            const int i = i0 + q;
            if (i < 13) {
                const float v = fmaxf(acc[q], 0.f);
                const u16 h = f2bf(v);
                const int da = ((i + 1) * 15 + (j + 1)) * 8 + o;
                Ah[da]        = h;
                Ah[da + 3600] = f2bf(v - bf2f(h));
            }
        }
    }
    __syncthreads();

    // zero B region (sX dead)
    for (int i = tid + 900; i < 1800; i += TPB) z4[i] = Z;
    __syncthreads();

    conv8(Ah, Bh, W, wave, lane, 0);               // L2: A8 -> B16
    __syncthreads();

    for (int i = tid; i < 900; i += TPB) z4[i] = Z; // zero A region
    __syncthreads();

    conv16(Bh, Ah, W + 384, wave, lane, 1);        // L3
    __syncthreads();
    conv16(Ah, Bh, W + 1024, wave, lane, 2);       // L4
    __syncthreads();
    conv16(Bh, Ah, W + 1664, wave, lane, 3);       // L5
    __syncthreads();

    // zero sF region [14400,19008) = z4[900,1188)
    for (int i = tid + 900; i < 1188; i += TPB) z4[i] = Z;
    __syncthreads();

    // ---- L6: 5x5 s2 p1, 16->32, i,j<5, no ReLU -> sF [32][6][6] planar
    {
        const short8* Wt6 = W + 2304;
        const int mt   = wave >> 1;
        const int nh   = wave & 1;
        const int lhi  = lane >> 4;
        const int hsel = lhi & 1;
        const int tsel = lhi >> 1;
        const int o    = nh * 16 + (lane & 15);
        const int pr = mt * 16 + (lane & 15);
        const int pe = pr < 25 ? pr : 0;
        const int ia = (pe * 52) >> 8;            // pe/5
        const int ja = pe - 5 * ia;
        const u16* sh = Ah + hsel * 1800;
        const u16* sl = sh + 3600;
        f32x4 acc = {0.f, 0.f, 0.f, 0.f};
#pragma unroll 4
        for (int s = 0; s < 13; s++) {
            const int t  = 2 * s + tsel;
            const int tt = t > 24 ? 24 : t;
            const int kh = (tt * 52) >> 8;        // tt/5
            const int kw = tt - 5 * kh;
            const int px = (2 * ia + kh) * 15 + (2 * ja + kw);
            const short8 Ahi = *(const short8*)(sh + px * 8);
            const short8 Alo = *(const short8*)(sl + px * 8);
            const short8 Bh2 = Wt6[((s * 2 + 0) * 2 + nh) * 64 + lane];
            const short8 Bl2 = Wt6[((s * 2 + 1) * 2 + nh) * 64 + lane];
            acc = MFMA(Ahi, Bh2, acc);
            acc = MFMA(Alo, Bh2, acc);
            acc = MFMA(Ahi, Bl2, acc);
        }
        const int p0 = mt * 16 + lhi * 4;
#pragma unroll
        for (int r = 0; r < 4; r++) {
            const int pp = p0 + r;
            if (pp < 25) {
                const int ii = (pp * 52) >> 8;
                const int jj = pp - 5 * ii;
                sF[o * 36 + ii * 6 + jj] = acc[r];
            }
        }
    }
    __syncthreads();

    // ---- FC: logits[c] = sF . Wfc[c] + bfc[c]
    if (tid < 160) {
        const int c = tid >> 4;
        const int l = tid & 15;
        const float4* fv = (const float4*)(sF + l * 72);
        const float4* wv = (const float4*)(Wfc + c * 1152 + l * 72);
        float p = 0.f;
#pragma unroll
        for (int m = 0; m < 18; m++) {
            const float4 a = fv[m];
            const float4 b = wv[m];
            p = fmaf(a.x, b.x, p);
            p = fmaf(a.y, b.y, p);
            p = fmaf(a.z, b.z, p);
            p = fmaf(a.w, b.w, p);
        }
        p += __shfl_down(p, 8, 16);
        p += __shfl_down(p, 4, 16);
        p += __shfl_down(p, 2, 16);
        p += __shfl_down(p, 1, 16);
        if (l == 0) sLog[c] = p + bfc[c];
    }
    __syncthreads();

    // ---- softmax
    if (tid < 10) {
        float mx = sLog[0];
#pragma unroll
        for (int k = 1; k < 10; k++) mx = fmaxf(mx, sLog[k]);
        float s = 0.f;
#pragma unroll
        for (int k = 0; k < 10; k++) s += expf(sLog[k] - mx);
        out[(size_t)img * 10 + tid] = expf(sLog[tid] - mx) / s;
    }
}

extern "C" void kernel_launch(void* const* d_in, const int* in_sizes, int n_in,
                              void* d_out, int out_size, void* d_ws, size_t ws_size,
                              hipStream_t stream) {
    const float* x   = (const float*)d_in[0];
    const float* K1  = (const float*)d_in[1];
    const float* K2  = (const float*)d_in[2];
    const float* K3  = (const float*)d_in[3];
    const float* K4  = (const float*)d_in[4];
    const float* K5  = (const float*)d_in[5];
    const float* K6  = (const float*)d_in[6];
    const float* Wfc = (const float*)d_in[7];
    const float* bfc = (const float*)d_in[8];
    float* out = (float*)d_out;
    short8* W = (short8*)d_ws;

    prep_w<<<22, TPB, 0, stream>>>(K2, K3, K4, K5, K6, W);

    const int B = in_sizes[0] / 2352;   // 8192
    cnn_fused<<<B, TPB, 0, stream>>>(x, K1, Wfc, bfc, W, out);
}

// Round 7
// 213.594 us; speedup vs baseline: 2.6013x; 1.0306x over previous
//
#include <hip/hip_runtime.h>
#include <math.h>

#define TPB 256

typedef __attribute__((ext_vector_type(8))) short short8;
typedef __attribute__((ext_vector_type(4))) float f32x4;
typedef unsigned short u16;

__device__ __forceinline__ f32x4 MFMA(short8 a, short8 b, f32x4 c) {
    return __builtin_amdgcn_mfma_f32_16x16x32_bf16(a, b, c, 0, 0, 0);
}
__device__ __forceinline__ u16 f2bf(float f) {
    unsigned int u = __builtin_bit_cast(unsigned int, f);
    u += 0x7FFFu + ((u >> 16) & 1u);            // RNE
    return (u16)(u >> 16);
}
__device__ __forceinline__ float bf2f(u16 h) {
    unsigned int u = ((unsigned int)h) << 16;
    return __builtin_bit_cast(float, u);
}

// ============ weight-fragment pre-kernel ============
// ws layout (short8 slots): entry = slot>>6, lane = slot&63.
//  K2:  ent [0,6)    = s*2+hl                 (s<3)
//  K3:  ent [6,16)   = 6  + s*2+hl            (s<5)
//  K4:  ent [16,26)  = 16 + s*2+hl
//  K5:  ent [26,36)  = 26 + s*2+hl
//  K6:  ent [36,88)  = 36 + s*4+hl*2+nh       (s<13, nh = cout half)
//  K1:  ent [88,96)  = 88 + s*2+hl            (s<4; k' = (c*5+kh)*8+kw, kw 5..7 pad)
extern "C" __global__ void prep_w(const float* __restrict__ K1, const float* __restrict__ K2,
                                  const float* __restrict__ K3, const float* __restrict__ K4,
                                  const float* __restrict__ K5, const float* __restrict__ K6,
                                  short8* __restrict__ W)
{
    const int slot = blockIdx.x * blockDim.x + threadIdx.x;
    if (slot >= 6144) return;
    const int lane = slot & 63;
    const int ent  = slot >> 6;
    const int o    = lane & 15;
    const int lhi  = lane >> 4;
    float w[8];
    int hl;
    if (ent < 6) {                       // K2: k' = tap*8 + c, tap = s*4+lhi
        const int s = ent >> 1; hl = ent & 1;
        const int t = s * 4 + lhi;
#pragma unroll
        for (int j = 0; j < 8; j++)
            w[j] = (t < 9) ? K2[(j * 9 + t) * 16 + o] : 0.f;
    } else if (ent < 36) {               // K3/4/5: k' = tap*16 + c
        const int e  = ent - 6;
        const float* Kg = (e < 10) ? K3 : (e < 20) ? K4 : K5;
        const int el = e % 10;
        const int s  = el >> 1; hl = el & 1;
        const int chalf = (lhi & 1) * 8;
        const int t = 2 * s + (lhi >> 1);
#pragma unroll
        for (int j = 0; j < 8; j++)
            w[j] = (t < 9) ? Kg[((chalf + j) * 9 + t) * 16 + o] : 0.f;
    } else if (ent < 88) {               // K6: k' = tap*16 + c, tap<25
        const int e = ent - 36;
        const int s = e >> 2; hl = (e >> 1) & 1;
        const int nh = e & 1;
        const int chalf = (lhi & 1) * 8;
        const int t  = 2 * s + (lhi >> 1);
        const int oo = nh * 16 + o;
#pragma unroll
        for (int j = 0; j < 8; j++)
            w[j] = (t < 25) ? K6[((chalf + j) * 25 + t) * 32 + oo] : 0.f;
    } else {                             // K1: group g = s*4+lhi = c*5+kh (g=15 pad), j=kw (5..7 pad)
        const int e = ent - 88;
        const int s = e >> 1; hl = e & 1;
        const int g  = s * 4 + lhi;
        const int gc = g > 14 ? 14 : g;
        const int c  = (gc * 52) >> 8;   // gc/5
        const int kh = gc - 5 * c;
#pragma unroll
        for (int j = 0; j < 8; j++)
            w[j] = (g < 15 && o < 8 && j < 5) ? K1[(c * 25 + kh * 5 + j) * 8 + o] : 0.f;
    }
    short8 v;
#pragma unroll
    for (int j = 0; j < 8; j++) {
        const u16 h = f2bf(w[j]);
        v[j] = hl ? (short)f2bf(w[j] - bf2f(h)) : (short)h;
    }
    W[slot] = v;
}

// ============ conv helpers (half-channel-plane LDS layout) ============
// 16-ch tensor @ base (shorts): hi half0 [0,1800), hi half1 [1800,3600),
//                               lo half0 [3600,5400), lo half1 [5400,7200)
// pixel stride = 8 shorts = 16 B. All writes interior-only: pad rings stay
// zero from the single full-LDS clear at kernel start.

__device__ __forceinline__ void conv8(const u16* __restrict__ s0,   // 8-ch src: hi [0,1800), lo +3600
                                      u16* __restrict__ d0,
                                      const short8* __restrict__ Wt,
                                      int wave, int lane, int rot)
{
    const int o   = lane & 15;
    const int lhi = lane >> 4;
    short8 Bhi[3], Blo[3];
#pragma unroll
    for (int s = 0; s < 3; s++) {
        Bhi[s] = Wt[(s * 2 + 0) * 64 + lane];
        Blo[s] = Wt[(s * 2 + 1) * 64 + lane];
    }
    const u16* sl = s0 + 3600;
    const int r0 = lane & 15;

    auto tile = [&](int m) {
        const int p  = m * 16 + r0;
        const int ip = (p * 683) >> 13;          // p/12
        const int jp = p - 12 * ip;
        f32x4 acc = {0.f, 0.f, 0.f, 0.f};
#pragma unroll
        for (int s = 0; s < 3; s++) {
            const int t  = s * 4 + lhi;
            const int tt = t > 8 ? 8 : t;
            const int kh = (tt * 11) >> 5;       // tt/3
            const int kw = tt - 3 * kh;
            const int px = (ip + kh) * 15 + (jp + kw);
            const short8 Ahi = *(const short8*)(s0 + px * 8);
            const short8 Alo = *(const short8*)(sl + px * 8);
            acc = MFMA(Ahi, Bhi[s], acc);
            acc = MFMA(Alo, Bhi[s], acc);
            acc = MFMA(Ahi, Blo[s], acc);
        }
        const int p0 = m * 16 + lhi * 4;
#pragma unroll
        for (int r = 0; r < 4; r++) {
            const int pp = p0 + r;
            const int ii = (pp * 683) >> 13;
            const int jj = pp - 12 * ii;
            const float v = fmaxf(acc[r], 0.f);
            const u16 h = f2bf(v);
            const int px2 = (ii + 1) * 15 + (jj + 1);
            const int da  = (o >> 3) * 1800 + px2 * 8 + (o & 7);
            d0[da]        = h;
            d0[da + 3600] = f2bf(v - bf2f(h));
        }
    };
    const int m0 = (wave + rot) & 3;
    tile(m0);
    tile(m0 + 4);
    if (m0 == 0) tile(8);
}

__device__ __forceinline__ void conv16(const u16* __restrict__ s0,
                                       u16* __restrict__ d0,
                                       const short8* __restrict__ Wt,
                                       int wave, int lane, int rot)
{
    const int o    = lane & 15;
    const int lhi  = lane >> 4;
    const int hsel = lhi & 1;
    const int tsel = lhi >> 1;
    short8 Bhi[5], Blo[5];
#pragma unroll
    for (int s = 0; s < 5; s++) {
        Bhi[s] = Wt[(s * 2 + 0) * 64 + lane];
        Blo[s] = Wt[(s * 2 + 1) * 64 + lane];
    }
    const u16* sh = s0 + hsel * 1800;
    const u16* sl = sh + 3600;
    const int r0 = lane & 15;

    auto tile = [&](int m) {
        const int p  = m * 16 + r0;
        const int ip = (p * 683) >> 13;
        const int jp = p - 12 * ip;
        f32x4 acc = {0.f, 0.f, 0.f, 0.f};
#pragma unroll
        for (int s = 0; s < 5; s++) {
            const int t  = 2 * s + tsel;
            const int tt = t > 8 ? 8 : t;
            const int kh = (tt * 11) >> 5;
            const int kw = tt - 3 * kh;
            const int px = (ip + kh) * 15 + (jp + kw);
            const short8 Ahi = *(const short8*)(sh + px * 8);
            const short8 Alo = *(const short8*)(sl + px * 8);
            acc = MFMA(Ahi, Bhi[s], acc);
            acc = MFMA(Alo, Bhi[s], acc);
            acc = MFMA(Ahi, Blo[s], acc);
        }
        const int p0 = m * 16 + lhi * 4;
#pragma unroll
        for (int r = 0; r < 4; r++) {
            const int pp = p0 + r;
            const int ii = (pp * 683) >> 13;
            const int jj = pp - 12 * ii;
            const float v = fmaxf(acc[r], 0.f);
            const u16 h = f2bf(v);
            const int px2 = (ii + 1) * 15 + (jj + 1);
            const int da  = (o >> 3) * 1800 + px2 * 8 + (o & 7);
            d0[da]        = h;
            d0[da + 3600] = f2bf(v - bf2f(h));
        }
    };
    const int m0 = (wave + rot) & 3;
    tile(m0);
    tile(m0 + 4);
    if (m0 == 0) tile(8);
}

// ============ main fused kernel ============
extern "C" __global__ void __launch_bounds__(TPB)
cnn_fused(const float* __restrict__ xg,
          const float* __restrict__ Wfc, const float* __restrict__ bfc,
          const short8* __restrict__ W, float* __restrict__ out)
{
    // byte map (all regions zeroed once; every later write is interior-only):
    //  S [0,11520)      : image bf16 [3][30][32] hi, lo at +5760 B; later sF f32[1152]
    //  A [11520,25920)  : 16-ch tensor (hi0,hi1,lo0,lo1 planes of 1800 shorts)
    //  B [25920,40320)  : 16-ch tensor; L1 writes 8-ch planes (hi [0,1800), lo +3600)
    //  sLog [40320,40360)
    __shared__ __align__(16) unsigned char smem[40384];
    u16*   const Sh   = (u16*)smem;               // 2880 shorts, lo at +2880
    u16*   const Ah   = (u16*)(smem + 11520);
    u16*   const Bhp  = (u16*)(smem + 25920);
    float* const sF   = (float*)smem;
    float* const sLog = (float*)(smem + 40320);
    uint4* const z4   = (uint4*)smem;
    const uint4 Z = {0u, 0u, 0u, 0u};

    const int tid  = threadIdx.x;
    const int lane = tid & 63;
    const int wave = tid >> 6;
    const int img  = blockIdx.x;

    // single full clear (2524 x 16B): pad rings everywhere stay zero after this
    for (int i = tid; i < 2524; i += TPB) z4[i] = Z;
    __syncthreads();

    // stage image as bf16 hi/lo planar [3][30][32], interior rows 1..28 cols 1..28
    const float4* xi4 = (const float4*)(xg + (size_t)img * 2352);
    for (int i4 = tid; i4 < 588; i4 += TPB) {
        const float4 v = xi4[i4];
        const int c = i4 / 196;
        const int rem = i4 - c * 196;
        const int r = rem / 7;
        const int q = rem - r * 7;
        const int ad = c * 960 + (r + 1) * 32 + q * 4 + 1;
        const float vv[4] = {v.x, v.y, v.z, v.w};
#pragma unroll
        for (int e = 0; e < 4; e++) {
            const u16 h = f2bf(vv[e]);
            Sh[ad + e]        = h;
            Sh[ad + e + 2880] = f2bf(vv[e] - bf2f(h));
        }
    }
    __syncthreads();

    // ---- L1: 5x5 s2 p1, 3->8, 13x13 full, ReLU. MFMA split bf16.
    // k' = (c*5+kh)*8 + kw (kw padded to 8): A-frag = 8 contiguous cols of one row.
    {
        const short8* Wt1 = W + 5632;            // ent 88
        const int o   = lane & 15;
        const int lhi = lane >> 4;
        short8 B1h[4], B1l[4];
#pragma unroll
        for (int s = 0; s < 4; s++) {
            B1h[s] = Wt1[(s * 2 + 0) * 64 + lane];
            B1l[s] = Wt1[(s * 2 + 1) * 64 + lane];
        }
        const u16* slo = Sh + 2880;
        for (int m = wave; m < 11; m += 4) {
            const int p  = m * 16 + o;
            const int pc = p > 168 ? 168 : p;
            const int i = (pc * 316) >> 12;      // pc/13
            const int j = pc - 13 * i;
            f32x4 acc = {0.f, 0.f, 0.f, 0.f};
#pragma unroll
            for (int s = 0; s < 4; s++) {
                const int g  = s * 4 + lhi;
                const int gc = g > 14 ? 14 : g;
                const int c  = (gc * 52) >> 8;   // gc/5
                const int kh = gc - 5 * c;
                const int ad = c * 960 + (2 * i + kh) * 32 + 2 * j;
                const short8 Ahi = *(const short8*)(Sh + ad);
                const short8 Alo = *(const short8*)(slo + ad);
                acc = MFMA(Ahi, B1h[s], acc);
                acc = MFMA(Alo, B1h[s], acc);
                acc = MFMA(Ahi, B1l[s], acc);
            }
#pragma unroll
            for (int r = 0; r < 4; r++) {
                const int pp = m * 16 + lhi * 4 + r;
                if (pp < 169 && o < 8) {
                    const int ii = (pp * 316) >> 12;
                    const int jj = pp - 13 * ii;
                    const float v = fmaxf(acc[r], 0.f);
                    const u16 h = f2bf(v);
                    const int da = ((ii + 1) * 15 + (jj + 1)) * 8 + o;
                    Bhp[da]        = h;
                    Bhp[da + 3600] = f2bf(v - bf2f(h));
                }
            }
        }
    }
    __syncthreads();

    // S region is dead from here on. Zero the sF overlay NOW (it holds stale
    // bf16 image data): 1152 floats = 288 uint4. Four barriers separate this
    // from L6's first sF write; the loop touches only S while L2 touches A/B.
    for (int i = tid; i < 288; i += TPB) z4[i] = Z;

    conv8(Bhp, Ah, W, wave, lane, 0);              // L2: B8 -> A16
    __syncthreads();
    conv16(Ah, Bhp, W + 384, wave, lane, 1);       // L3: A -> B
    __syncthreads();
    conv16(Bhp, Ah, W + 1024, wave, lane, 2);      // L4: B -> A
    __syncthreads();
    conv16(Ah, Bhp, W + 1664, wave, lane, 3);      // L5: A -> B
    __syncthreads();

    // ---- L6: 5x5 s2 p1, 16->32, i,j<5, no ReLU -> sF [32][6][6] planar (in S).
    // sF is all-zero except the pp<25 interior written below, so the truncated
    // row/col 5 of each 6x6 map are zero for ALL 32 channels.
    {
        const short8* Wt6 = W + 2304;
        const int mt   = wave >> 1;
        const int nh   = wave & 1;
        const int lhi  = lane >> 4;
        const int hsel = lhi & 1;
        const int tsel = lhi >> 1;
        const int o    = nh * 16 + (lane & 15);
        const int pr = mt * 16 + (lane & 15);
        const int pe = pr < 25 ? pr : 0;
        const int ia = (pe * 52) >> 8;            // pe/5
        const int ja = pe - 5 * ia;
        const u16* sh = Bhp + hsel * 1800;
        const u16* sl = sh + 3600;
        f32x4 acc = {0.f, 0.f, 0.f, 0.f};
#pragma unroll 4
        for (int s = 0; s < 13; s++) {
            const int t  = 2 * s + tsel;
            const int tt = t > 24 ? 24 : t;
            const int kh = (tt * 52) >> 8;        // tt/5
            const int kw = tt - 5 * kh;
            const int px = (2 * ia + kh) * 15 + (2 * ja + kw);
            const short8 Ahi = *(const short8*)(sh + px * 8);
            const short8 Alo = *(const short8*)(sl + px * 8);
            const short8 Bh2 = Wt6[((s * 2 + 0) * 2 + nh) * 64 + lane];
            const short8 Bl2 = Wt6[((s * 2 + 1) * 2 + nh) * 64 + lane];
            acc = MFMA(Ahi, Bh2, acc);
            acc = MFMA(Alo, Bh2, acc);
            acc = MFMA(Ahi, Bl2, acc);
        }
        const int p0 = mt * 16 + lhi * 4;
#pragma unroll
        for (int r = 0; r < 4; r++) {
            const int pp = p0 + r;
            if (pp < 25) {
                const int ii = (pp * 52) >> 8;
                const int jj = pp - 5 * ii;
                sF[o * 36 + ii * 6 + jj] = acc[r];
            }
        }
    }
    __syncthreads();

    // ---- FC: logits[c] = sF . Wfc[c] + bfc[c]
    if (tid < 160) {
        const int c = tid >> 4;
        const int l = tid & 15;
        const float4* fv = (const float4*)(sF + l * 72);
        const float4* wv = (const float4*)(Wfc + c * 1152 + l * 72);
        float p = 0.f;
#pragma unroll
        for (int m = 0; m < 18; m++) {
            const float4 a = fv[m];
            const float4 b = wv[m];
            p = fmaf(a.x, b.x, p);
            p = fmaf(a.y, b.y, p);
            p = fmaf(a.z, b.z, p);
            p = fmaf(a.w, b.w, p);
        }
        p += __shfl_down(p, 8, 16);
        p += __shfl_down(p, 4, 16);
        p += __shfl_down(p, 2, 16);
        p += __shfl_down(p, 1, 16);
        if (l == 0) sLog[c] = p + bfc[c];
    }
    __syncthreads();

    // ---- softmax
    if (tid < 10) {
        float mx = sLog[0];
#pragma unroll
        for (int k = 1; k < 10; k++) mx = fmaxf(mx, sLog[k]);
        float s = 0.f;
#pragma unroll
        for (int k = 0; k < 10; k++) s += expf(sLog[k] - mx);
        out[(size_t)img * 10 + tid] = expf(sLog[tid] - mx) / s;
    }
}

extern "C" void kernel_launch(void* const* d_in, const int* in_sizes, int n_in,
                              void* d_out, int out_size, void* d_ws, size_t ws_size,
                              hipStream_t stream) {
    const float* x   = (const float*)d_in[0];
    const float* K1  = (const float*)d_in[1];
    const float* K2  = (const float*)d_in[2];
    const float* K3  = (const float*)d_in[3];
    const float* K4  = (const float*)d_in[4];
    const float* K5  = (const float*)d_in[5];
    const float* K6  = (const float*)d_in[6];
    const float* Wfc = (const float*)d_in[7];
    const float* bfc = (const float*)d_in[8];
    float* out = (float*)d_out;
    short8* W = (short8*)d_ws;

    prep_w<<<24, TPB, 0, stream>>>(K1, K2, K3, K4, K5, K6, W);

    const int B = in_sizes[0] / 2352;   // 8192
    cnn_fused<<<B, TPB, 0, stream>>>(x, Wfc, bfc, W, out);
}